// Round 3
// baseline (548.930 us; speedup 1.0000x reference)
//
#include <hip/hip_runtime.h>
#include <hip/hip_cooperative_groups.h>
#include <math.h>

namespace cg = cooperative_groups;

// Closed-form reformulation of the T=65536-step scan (DIM=512, fp32):
//   D_t = v + c*t ; var_t = (v-c) D_t / D_{t-1} ; mu_t = ((v-c)mu0 + c Z_t)/D_{t-1}
//   Z_t = exclusive per-column prefix sum of z.
//   lkd = analytic_logdet (telescopes) - Sum_{t,d} (z-mu_t)^2 * D_{t-1} / (2(v-c)D_t)
// Single cooperative kernel, 4 phases separated by grid.sync():
//   P1 all blocks: chunk colsums          (z read #1, 128 MB HBM)
//   P2 blocks 0..63: per-group excl scan  (4 MB in L2)
//   P3 block 0: group-total scan + analytic logdet -> out[0]
//   P4 all blocks: quadratic main pass    (z read #2, mostly L3-resident)
// Workspace: BLOCKS*DIM + GROUPS*DIM floats = 2 MB + 128 KB.

#define DIM    512
#define TT     65536
#define BLOCKS 1024
#define ROWS   64      // TT / BLOCKS
#define GROUPS 64
#define CPG    16      // BLOCKS / GROUPS
#define TWO_PI 6.283185307179586

__global__ __launch_bounds__(128, 2) void fused_all(
        const float* __restrict__ z,
        const float* __restrict__ var_vbl,
        const float* __restrict__ corr_vbl,
        const float* __restrict__ prior_mu,
        float* __restrict__ out,
        float* __restrict__ sums,
        float* __restrict__ gsums) {
    cg::grid_group grid = cg::this_grid();
    const int chunk = blockIdx.x;
    const int tid = threadIdx.x;   // 0..127, owns 4 contiguous columns

    __shared__ double red[128];

    // ---- Phase 1: per-chunk column sums (float4) ----
    {
        const float4* zp = reinterpret_cast<const float4*>(z)
                           + (size_t)chunk * ROWS * (DIM / 4) + tid;
        float4 s = make_float4(0.f, 0.f, 0.f, 0.f);
#pragma unroll 8
        for (int r = 0; r < ROWS; ++r) {
            float4 v = zp[(size_t)r * (DIM / 4)];
            s.x += v.x; s.y += v.y; s.z += v.z; s.w += v.w;
        }
        reinterpret_cast<float4*>(sums)[(size_t)chunk * (DIM / 4) + tid] = s;
    }
    grid.sync();

    // ---- Phase 2: within-group exclusive scan (blocks 0..GROUPS-1) ----
    if (chunk < GROUPS) {
        const int g = chunk;
        float4 run = make_float4(0.f, 0.f, 0.f, 0.f);
#pragma unroll
        for (int i = 0; i < CPG; ++i) {
            float4* p = reinterpret_cast<float4*>(sums)
                        + (size_t)(g * CPG + i) * (DIM / 4) + tid;
            float4 t = *p;
            *p = run;
            run.x += t.x; run.y += t.y; run.z += t.z; run.w += t.w;
        }
        reinterpret_cast<float4*>(gsums)[(size_t)g * (DIM / 4) + tid] = run;
    }
    grid.sync();

    // ---- Phase 3: exclusive scan over group totals + analytic logdet (block 0) ----
    if (chunk == 0) {
        float4 run = make_float4(0.f, 0.f, 0.f, 0.f);
#pragma unroll 8
        for (int g = 0; g < GROUPS; ++g) {
            float4* p = reinterpret_cast<float4*>(gsums)
                        + (size_t)g * (DIM / 4) + tid;
            float4 t = *p;
            *p = run;
            run.x += t.x; run.y += t.y; run.z += t.z; run.w += t.w;
        }
        // sum_t -0.5*log(2pi var_t) telescopes:
        //   -0.5*[T*log(2pi(v-c)) + log(D_{T-1}/(v-c))] per column.
        double Lsum = 0.0;
#pragma unroll
        for (int j = 0; j < 4; ++j) {
            const int d = tid * 4 + j;
            double sp = log1p(exp((double)var_vbl[d]));
            double v = sp * sp;
            double c = v / (1.0 + exp(-(double)corr_vbl[d]));
            double vmc = v - c;
            double Dlast = v + c * (double)(TT - 1);
            Lsum += -0.5 * ((double)TT * (log(TWO_PI) + log(vmc)) + log(Dlast / vmc));
        }
        red[tid] = Lsum;
        __syncthreads();
        for (int s = 64; s > 0; s >>= 1) {
            if (tid < s) red[tid] += red[tid + s];
            __syncthreads();
        }
        if (tid == 0) out[0] = (float)red[0];  // overwrite poison; P4 adds on top
    }
    grid.sync();

    // ---- Phase 4: quadratic main pass ----
    {
        const int d0 = tid * 4;
        const int g = chunk / CPG;
        const float t0m1 = (float)(chunk * ROWS) - 1.0f;

        float vv[4], cc[4], k0[4], kq[4], Z[4], Dprev[4], invDprev[4];
#pragma unroll
        for (int j = 0; j < 4; ++j) {
            const int d = d0 + j;
            float spv = log1pf(expf(var_vbl[d]));
            float v = spv * spv;
            float c = v / (1.0f + expf(-corr_vbl[d]));
            float vmc = v - c;
            vv[j] = v;
            cc[j] = c;
            k0[j] = vmc * prior_mu[d];          // (v-c)*mu0
            kq[j] = 0.5f / vmc;
            Z[j] = sums[(size_t)chunk * DIM + d] + gsums[(size_t)g * DIM + d];
            Dprev[j] = fmaf(c, t0m1, v);        // D_{t0-1}
            invDprev[j] = __builtin_amdgcn_rcpf(Dprev[j]);
        }

        const float4* zp = reinterpret_cast<const float4*>(z)
                           + (size_t)chunk * ROWS * (DIM / 4) + tid;
        float acc = 0.f;
        float tf = t0m1 + 1.0f;
#pragma unroll 4
        for (int r = 0; r < ROWS; ++r) {
            float4 zv = zp[(size_t)r * (DIM / 4)];
            float zz[4] = {zv.x, zv.y, zv.z, zv.w};
#pragma unroll
            for (int j = 0; j < 4; ++j) {
                float Dt = fmaf(cc[j], tf, vv[j]);            // v + c*t
                float invDt = __builtin_amdgcn_rcpf(Dt);
                float mu = fmaf(cc[j], Z[j], k0[j]) * invDprev[j];
                float e = zz[j] - mu;
                acc = fmaf(e * e * Dprev[j] * invDt, kq[j], acc);
                Z[j] += zz[j];
                Dprev[j] = Dt;
                invDprev[j] = invDt;
            }
            tf += 1.0f;
        }

        // block reduce (2 waves) and subtract from out
        for (int off = 32; off > 0; off >>= 1) acc += __shfl_down(acc, off, 64);
        __shared__ float wsred[2];
        const int lane = tid & 63, w = tid >> 6;
        if (lane == 0) wsred[w] = acc;
        __syncthreads();
        if (tid == 0) atomicAdd(out, -(wsred[0] + wsred[1]));
    }
}

extern "C" void kernel_launch(void* const* d_in, const int* in_sizes, int n_in,
                              void* d_out, int out_size, void* d_ws, size_t ws_size,
                              hipStream_t stream) {
    const float* z = (const float*)d_in[0];
    const float* var_vbl = (const float*)d_in[1];
    const float* corr_vbl = (const float*)d_in[2];
    const float* prior_mu = (const float*)d_in[3];
    float* out = (float*)d_out;
    float* sums = (float*)d_ws;                        // BLOCKS*DIM floats (2 MB)
    float* gsums = sums + (size_t)BLOCKS * DIM;        // GROUPS*DIM floats (128 KB)

    void* args[] = {(void*)&z, (void*)&var_vbl, (void*)&corr_vbl, (void*)&prior_mu,
                    (void*)&out, (void*)&sums, (void*)&gsums};
    hipLaunchCooperativeKernel((const void*)fused_all, dim3(BLOCKS), dim3(128),
                               args, 0, stream);
}

// Round 4
// 262.037 us; speedup vs baseline: 2.0949x; 2.0949x over previous
//
#include <hip/hip_runtime.h>
#include <math.h>

// Closed-form reformulation of the T=65536-step scan (DIM=512, fp32):
//   D_t = v + c*t ; mu_t = ((v-c)mu0 + c Z_t)/D_{t-1} ; 1/(2 var_t) = D_{t-1}/(2(v-c)D_t)
//   Z_t = exclusive per-column prefix sum of z.
// ONE pass over z: expand (z - mu_t)^2 weight in the chunk-base prefix Zc:
//   u = z - (k0 + c*zeta)/D_{t-1}  (zeta = chunk-local exclusive prefix)
//   p = c/D_{t-1} ;  w = D_{t-1}/(2(v-c)D_t)
//   chunk quad = A - 2*Zc*B + Zc^2*C,  A=sum w u^2, B=sum w u p, C=sum w p^2
// K1: stream z once, emit per-(chunk,col) {cs, A, B, C}. K2: per-column
// redundant prefix over cs + combine + analytic logdet + reduce.
// Workspace: 4 planes of CHUNKS*DIM floats = 8 MB.

#define DIM    512
#define TT     65536
#define CHUNKS 1024
#define ROWS   64      // TT / CHUNKS
#define K2B    64      // kernel-2 blocks
#define CPB    16      // CHUNKS / K2B
#define TWO_PI 6.283185307179586

// K1: grid=CHUNKS, block=128; thread owns 4 contiguous columns across ROWS rows.
__global__ __launch_bounds__(128) void k1_pass(const float* __restrict__ z,
                                               const float* __restrict__ var_vbl,
                                               const float* __restrict__ corr_vbl,
                                               const float* __restrict__ prior_mu,
                                               float* __restrict__ ws,
                                               float* __restrict__ out) {
    const int chunk = blockIdx.x;
    const int tid = threadIdx.x;        // 0..127
    const int d0 = tid * 4;
    const float t0m1 = (float)(chunk * ROWS) - 1.0f;

    if (chunk == 0 && tid == 0) out[0] = 0.0f;  // k2 atomicAdds on top

    float vv[4], cc[4], k0[4], kq[4], zeta[4], Dprev[4], invDprev[4];
    float A[4], B[4], C[4];
#pragma unroll
    for (int j = 0; j < 4; ++j) {
        const int d = d0 + j;
        float spv = log1pf(expf(var_vbl[d]));
        float v = spv * spv;
        float c = v / (1.0f + expf(-corr_vbl[d]));
        float vmc = v - c;
        vv[j] = v; cc[j] = c;
        k0[j] = vmc * prior_mu[d];
        kq[j] = 0.5f / vmc;
        zeta[j] = 0.f;
        Dprev[j] = fmaf(c, t0m1, v);
        invDprev[j] = __builtin_amdgcn_rcpf(Dprev[j]);
        A[j] = 0.f; B[j] = 0.f; C[j] = 0.f;
    }

    const float4* zp = reinterpret_cast<const float4*>(z)
                       + (size_t)chunk * ROWS * (DIM / 4) + tid;
    float tf = t0m1 + 1.0f;
#pragma unroll 4
    for (int r = 0; r < ROWS; ++r) {
        float4 zv = zp[(size_t)r * (DIM / 4)];
        float zz[4] = {zv.x, zv.y, zv.z, zv.w};
#pragma unroll
        for (int j = 0; j < 4; ++j) {
            float Dt = fmaf(cc[j], tf, vv[j]);
            float invDt = __builtin_amdgcn_rcpf(Dt);
            float u = zz[j] - fmaf(cc[j], zeta[j], k0[j]) * invDprev[j];
            float w = Dprev[j] * invDt * kq[j];
            float p = cc[j] * invDprev[j];
            float wu = w * u;
            float wp = w * p;
            A[j] = fmaf(wu, u, A[j]);
            B[j] = fmaf(wu, p, B[j]);
            C[j] = fmaf(wp, p, C[j]);
            zeta[j] += zz[j];
            Dprev[j] = Dt;
            invDprev[j] = invDt;
        }
        tf += 1.0f;
    }

    const size_t base = (size_t)chunk * (DIM / 4) + tid;
    const size_t plane = (size_t)CHUNKS * (DIM / 4);
    float4* w4 = reinterpret_cast<float4*>(ws);
    w4[base]             = make_float4(zeta[0], zeta[1], zeta[2], zeta[3]);
    w4[base + plane]     = make_float4(A[0], A[1], A[2], A[3]);
    w4[base + 2 * plane] = make_float4(B[0], B[1], B[2], B[3]);
    w4[base + 3 * plane] = make_float4(C[0], C[1], C[2], C[3]);
}

// K2: grid=K2B, block=512. Thread d owns column d. Block g handles chunks
// [g*CPB, (g+1)*CPB); redundantly computes its Zc base from cs (L2/L3-hot).
__global__ __launch_bounds__(512) void k2_combine(const float* __restrict__ ws,
                                                  const float* __restrict__ var_vbl,
                                                  const float* __restrict__ corr_vbl,
                                                  float* __restrict__ out) {
    const int g = blockIdx.x;
    const int d = threadIdx.x;          // 0..511
    const float* cs = ws;
    const float* Ap = ws + (size_t)CHUNKS * DIM;
    const float* Bp = Ap + (size_t)CHUNKS * DIM;
    const float* Cp = Bp + (size_t)CHUNKS * DIM;

    // Phase A: Zc base = sum of cs over chunks < g*CPB (coalesced, 4-way ILP).
    const int lim = g * CPB;
    float z0 = 0.f, z1 = 0.f, z2 = 0.f, z3 = 0.f;
    for (int i = 0; i + 3 < lim; i += 4) {
        z0 += cs[(size_t)i * DIM + d];
        z1 += cs[(size_t)(i + 1) * DIM + d];
        z2 += cs[(size_t)(i + 2) * DIM + d];
        z3 += cs[(size_t)(i + 3) * DIM + d];
    }
    float Zc = (z0 + z1) + (z2 + z3);

    // Phase B: combine this block's chunks.
    float q = 0.f;
#pragma unroll
    for (int i = 0; i < CPB; ++i) {
        const size_t idx = (size_t)(g * CPB + i) * DIM + d;
        q += Ap[idx] - 2.0f * Zc * Bp[idx] + Zc * Zc * Cp[idx];
        Zc += cs[idx];
    }

    double contrib = -(double)q;
    if (g == 0) {
        // analytic logdet: -0.5*[T*log(2pi(v-c)) + log(D_{T-1}/(v-c))] per column
        double sp = log1p(exp((double)var_vbl[d]));
        double v = sp * sp;
        double c = v / (1.0 + exp(-(double)corr_vbl[d]));
        double vmc = v - c;
        double Dlast = v + c * (double)(TT - 1);
        contrib += -0.5 * ((double)TT * (log(TWO_PI) + log(vmc)) + log(Dlast / vmc));
    }

    __shared__ double red[512];
    red[d] = contrib;
    __syncthreads();
    for (int s = 256; s > 0; s >>= 1) {
        if (d < s) red[d] += red[d + s];
        __syncthreads();
    }
    if (d == 0) atomicAdd(out, (float)red[0]);
}

extern "C" void kernel_launch(void* const* d_in, const int* in_sizes, int n_in,
                              void* d_out, int out_size, void* d_ws, size_t ws_size,
                              hipStream_t stream) {
    const float* z = (const float*)d_in[0];
    const float* var_vbl = (const float*)d_in[1];
    const float* corr_vbl = (const float*)d_in[2];
    const float* prior_mu = (const float*)d_in[3];
    float* out = (float*)d_out;
    float* ws = (float*)d_ws;   // 4 planes x CHUNKS*DIM floats = 8 MB

    k1_pass<<<CHUNKS, 128, 0, stream>>>(z, var_vbl, corr_vbl, prior_mu, ws, out);
    k2_combine<<<K2B, 512, 0, stream>>>(ws, var_vbl, corr_vbl, out);
}